// Round 1
// baseline (8997.761 us; speedup 1.0000x reference)
//
#include <hip/hip_runtime.h>

typedef _Float16 f16;
typedef _Float16 f16x8 __attribute__((ext_vector_type(8)));
typedef float f32x4 __attribute__((ext_vector_type(4)));

constexpr int NB = 8;        // batch
constexpr int SEQ = 512;     // seq len
constexpr int ED = 512;      // embed dim
constexpr int HD = 512;      // hidden
constexpr int NROWS = NB * SEQ;   // 4096
constexpr int GD = 4 * HD;        // 2048 gate cols

__device__ __forceinline__ float wred_sum(float v) {
    #pragma unroll
    for (int off = 32; off > 0; off >>= 1) v += __shfl_xor(v, off, 64);
    return v;
}
__device__ __forceinline__ float wred_max(float v) {
    #pragma unroll
    for (int off = 32; off > 0; off >>= 1) v = fmaxf(v, __shfl_xor(v, off, 64));
    return v;
}

// ---------------- generic f16-MFMA GEMM: C = A(f32,MxK) @ B + bias ----------
// BT=0: B is row-major KxN (ldb = row stride). BT=1: B is row-major NxK.
// 128x128 tile per 256-thread block; wave computes 64x64 via 4x4 mfma_16x16x32.
template<int BT>
__global__ __launch_bounds__(256)
void gemm_f16(const float* __restrict__ A, int lda, long long strideA,
              const float* __restrict__ Bm, int ldb, long long strideB,
              const float* __restrict__ bias,
              float* __restrict__ C, int ldc, long long strideC, int K)
{
    __shared__ f16 As[128][40];   // pad 40 to break bank conflicts
    __shared__ f16 Bs[128][40];   // stored as [n][k]
    A  += (size_t)blockIdx.z * strideA;
    Bm += (size_t)blockIdx.z * strideB;
    C  += (size_t)blockIdx.z * strideC;
    const int tid = threadIdx.x;
    const int gM = blockIdx.y * 128;
    const int gN = blockIdx.x * 128;
    const int wave = tid >> 6, lane = tid & 63;
    const int wm = (wave >> 1) * 64, wn = (wave & 1) * 64;
    const int fl = lane & 15, fq = lane >> 4;
    f32x4 acc[4][4];
    #pragma unroll
    for (int i = 0; i < 4; i++)
        #pragma unroll
        for (int j = 0; j < 4; j++) acc[i][j] = (f32x4){0.f, 0.f, 0.f, 0.f};

    const int arow = tid >> 1;
    const int akg  = (tid & 1) * 16;
    const int bn   = tid & 127;
    const int bkg  = (tid >> 7) * 16;

    for (int k0 = 0; k0 < K; k0 += 32) {
        __syncthreads();
        {   // stage A tile 128x32 (fp32 -> f16)
            const float* src = A + (size_t)(gM + arow) * lda + k0 + akg;
            f16* dst = &As[arow][akg];
            #pragma unroll
            for (int u = 0; u < 16; u += 4) {
                float4 v = *(const float4*)(src + u);
                dst[u+0]=(f16)v.x; dst[u+1]=(f16)v.y; dst[u+2]=(f16)v.z; dst[u+3]=(f16)v.w;
            }
        }
        if (BT) {
            const float* src = Bm + (size_t)(gN + arow) * ldb + k0 + akg;
            f16* dst = &Bs[arow][akg];
            #pragma unroll
            for (int u = 0; u < 16; u += 4) {
                float4 v = *(const float4*)(src + u);
                dst[u+0]=(f16)v.x; dst[u+1]=(f16)v.y; dst[u+2]=(f16)v.z; dst[u+3]=(f16)v.w;
            }
        } else {
            const float* src = Bm + (size_t)(k0 + bkg) * ldb + gN + bn;
            #pragma unroll
            for (int u = 0; u < 16; u++)
                Bs[bn][bkg + u] = (f16)src[(size_t)u * ldb];
        }
        __syncthreads();
        f16x8 af[4], bf[4];
        #pragma unroll
        for (int i = 0; i < 4; i++) af[i] = *(const f16x8*)&As[wm + 16*i + fl][fq*8];
        #pragma unroll
        for (int j = 0; j < 4; j++) bf[j] = *(const f16x8*)&Bs[wn + 16*j + fl][fq*8];
        #pragma unroll
        for (int i = 0; i < 4; i++)
            #pragma unroll
            for (int j = 0; j < 4; j++)
                acc[i][j] = __builtin_amdgcn_mfma_f32_16x16x32_f16(af[i], bf[j], acc[i][j], 0, 0, 0);
    }
    #pragma unroll
    for (int j = 0; j < 4; j++) {
        const int col = gN + wn + 16*j + fl;
        const float bv = bias ? bias[col] : 0.f;
        #pragma unroll
        for (int i = 0; i < 4; i++) {
            const int row0 = gM + wm + 16*i + fq*4;
            #pragma unroll
            for (int r = 0; r < 4; r++)
                C[(size_t)(row0 + r) * ldc + col] = acc[i][j][r] + bv;
        }
    }
}

// ---------------- persistent BiLSTM layer --------------------------------
// 128 blocks x 128 threads: blocks [0,64) = forward, [64,128) = backward.
// Each WG owns 8 hidden units (32 gate cols); W-slice (512x32) lives in LDS
// as f16. Per step: recurrent matmul via MFMA, fp32 gate math, h double-
// buffered in global; cross-WG sync via per-WG slot stores + wave-poll.
constexpr int LWG = 64;          // WGs per direction
constexpr int JW = HD / LWG;     // 8 hidden units per WG
constexpr int LK = 520;          // padded LDS k-stride (f16 elems)

__global__ __launch_bounds__(128)
void lstm_layer(const float* __restrict__ xgf, const float* __restrict__ xgb,
                const float* __restrict__ Wfull_f, const float* __restrict__ Wfull_b, int rowOff,
                const float* __restrict__ h0f, const float* __restrict__ c0f,
                const float* __restrict__ h0b, const float* __restrict__ c0b,
                const int* __restrict__ xtok,
                float* __restrict__ outbuf,     // [4096][1024], cols dir*512 + j
                float* __restrict__ hbuf,       // [2 dirs][2 phases][8][512]
                unsigned int* __restrict__ slots) // [2 dirs][64]
{
    __shared__ f16 Ws[32 * LK];      // [local col][k]
    __shared__ f16 hsf[16 * LK];     // [m=batch(pad to 16)][k]; rows 8-15 unused garbage
    __shared__ float gates[8][32];
    __shared__ float cst[8][JW];

    const int bid = blockIdx.x;
    const int dir = bid >> 6;
    const int wg  = bid & 63;
    const int j0  = wg * JW;
    const int tid = threadIdx.x;
    const float* xg = dir ? xgb : xgf;
    const float* Wr = (dir ? Wfull_b : Wfull_f) + (size_t)rowOff * GD;  // h-part rows
    const float* h0 = dir ? h0b : h0f;
    const float* c0 = dir ? c0b : c0f;
    float* hb = hbuf + dir * (2 * NB * HD);
    unsigned int* slot = slots + dir * LWG;

    // preload W slice into LDS (once)
    for (int idx = tid; idx < 32 * 512; idx += 128) {
        const int k  = idx >> 5;
        const int lc = idx & 31;                      // gate*8 + j
        const int gcol = (lc >> 3) * HD + j0 + (lc & 7);
        Ws[lc * LK + k] = (f16)Wr[(size_t)k * GD + gcol];
    }
    // init state
    if (tid < 64) {
        const int j = tid & 7, b = tid >> 3;
        cst[b][j] = c0[j0 + j];
        hb[b * HD + j0 + j] = h0[j0 + j];             // phase buffer 0
    }
    __syncthreads();
    if (tid == 0) __hip_atomic_store(&slot[wg], 1u, __ATOMIC_RELEASE, __HIP_MEMORY_SCOPE_AGENT);

    const int lane = tid & 63;
    const int wv = tid >> 6;       // wave -> n-tile (16 cols each)
    const int fl = lane & 15;
    const int fq = lane >> 4;

    for (int s = 0; s < SEQ; s++) {
        const int t = dir ? (SEQ - 1 - s) : s;
        const unsigned target = (unsigned)(s + 1);
        if (tid < 64) {            // wave 0 polls all 64 slots of this dir
            while (true) {
                unsigned v = __hip_atomic_load(&slot[tid], __ATOMIC_ACQUIRE, __HIP_MEMORY_SCOPE_AGENT);
                if (__all(v >= target)) break;
                __builtin_amdgcn_s_sleep(2);
            }
        }
        __syncthreads();
        {   // stage h (fp32 global -> f16 LDS), rows 0..7
            const float* src = hb + (s & 1) * (NB * HD);
            const int base = tid * 32;
            const int m = base >> 9;
            const int kk = base & 511;
            #pragma unroll
            for (int u = 0; u < 32; u += 4) {
                float4 v4 = *(const float4*)&src[base + u];
                f16* d = &hsf[m * LK + kk + u];
                d[0]=(f16)v4.x; d[1]=(f16)v4.y; d[2]=(f16)v4.z; d[3]=(f16)v4.w;
            }
        }
        __syncthreads();
        f32x4 acc = {0.f, 0.f, 0.f, 0.f};
        #pragma unroll
        for (int kc = 0; kc < 16; kc++) {
            f16x8 a  = *(const f16x8*)&hsf[fl * LK + kc * 32 + fq * 8];
            f16x8 bb = *(const f16x8*)&Ws[(wv * 16 + fl) * LK + kc * 32 + fq * 8];
            acc = __builtin_amdgcn_mfma_f32_16x16x32_f16(a, bb, acc, 0, 0, 0);
        }
        if (fq < 2) {              // D rows 0..7 = batches; add precomputed x-gates
            const int lc = wv * 16 + fl;
            const int gcol = (lc >> 3) * HD + j0 + (lc & 7);
            #pragma unroll
            for (int r = 0; r < 4; r++) {
                const int b = fq * 4 + r;
                gates[b][lc] = acc[r] + xg[(size_t)(b * SEQ + t) * GD + gcol];
            }
        }
        __syncthreads();
        if (tid < 64) {
            const int j = tid & 7, b = tid >> 3;
            const float gi = gates[b][j],      gf = gates[b][8 + j];
            const float go = gates[b][16 + j], gg = gates[b][24 + j];
            const float cprev = cst[b][j];
            const float si = 1.f / (1.f + expf(-gi));
            const float sf = 1.f / (1.f + expf(-gf));
            const float so = 1.f / (1.f + expf(-go));
            const float cn = sf * cprev + si * tanhf(gg);
            const float hn = so * tanhf(cn);
            const bool act = xtok[b * SEQ + t] != 0;
            const float hprev = hb[(s & 1) * (NB * HD) + b * HD + j0 + j];
            cst[b][j] = act ? cn : cprev;
            hb[((s + 1) & 1) * (NB * HD) + b * HD + j0 + j] = act ? hn : hprev;
            outbuf[(size_t)(b * SEQ + t) * 1024 + dir * 512 + j0 + j] = act ? hn : 0.f;
        }
        __syncthreads();
        if (tid == 0) __hip_atomic_store(&slot[wg], (unsigned)(s + 2), __ATOMIC_RELEASE, __HIP_MEMORY_SCOPE_AGENT);
    }
}

// ---------------- small kernels ------------------------------------------
__global__ void init_slots(unsigned int* s) { s[threadIdx.x] = 0u; }

__global__ __launch_bounds__(128)
void embed_kernel(const int* __restrict__ xtok, const float* __restrict__ emb,
                  float* __restrict__ dst) {
    const int r = blockIdx.x;
    const int tok = xtok[r];
    const float4* src = (const float4*)(emb + (size_t)tok * ED);
    float4* d = (float4*)(dst + (size_t)r * ED);
    d[threadIdx.x] = src[threadIdx.x];
}

__global__ __launch_bounds__(256)
void copycat_kernel(const float* __restrict__ enc, float* __restrict__ cat) {
    const int r = blockIdx.x;
    const int i = threadIdx.x * 4;
    *(float4*)&cat[(size_t)r * 2048 + i] = *(const float4*)&enc[(size_t)r * 1024 + i];
}

__global__ __launch_bounds__(256)
void softmax_kernel(float* __restrict__ sc, const int* __restrict__ xtok) {
    __shared__ float sm[4];
    const int r = blockIdx.x;          // b*512 + q
    const int b = r >> 9;
    const bool validq = xtok[r] != 0;
    float* row = sc + (size_t)r * 512;
    const int tid = threadIdx.x;
    float v0 = row[tid] * 0.03125f;
    float v1 = row[tid + 256] * 0.03125f;
    v0 = (xtok[(b << 9) + tid]       != 0) ? v0 : -3.402823466e38f;
    v1 = (xtok[(b << 9) + tid + 256] != 0) ? v1 : -3.402823466e38f;
    if (!validq) { v0 = 0.f; v1 = 0.f; }
    float m = wred_max(fmaxf(v0, v1));
    if ((tid & 63) == 0) sm[tid >> 6] = m;
    __syncthreads();
    m = fmaxf(fmaxf(sm[0], sm[1]), fmaxf(sm[2], sm[3]));
    const float e0 = expf(v0 - m), e1 = expf(v1 - m);
    float ssum = wred_sum(e0 + e1);
    __syncthreads();
    if ((tid & 63) == 0) sm[tid >> 6] = ssum;
    __syncthreads();
    ssum = (sm[0] + sm[1]) + (sm[2] + sm[3]);
    const float inv = 1.f / ssum;
    row[tid]       = validq ? e0 * inv : 0.f;
    row[tid + 256] = validq ? e1 * inv : 0.f;
}

__global__ __launch_bounds__(256)
void ln1_kernel(const float* __restrict__ enc, const float* __restrict__ ao,
                const float* __restrict__ g, const float* __restrict__ be,
                const int* __restrict__ xtok, float* __restrict__ out) {
    __shared__ float sm[8];
    const int r = blockIdx.x;
    const bool valid = xtok[r] != 0;
    const float* er = enc + (size_t)r * 1024;
    const float* ar = ao + (size_t)r * 1024;
    float* orow = out + (size_t)r * 1024;
    const int tid = threadIdx.x;
    float v[4]; float s = 0.f, ss = 0.f;
    #pragma unroll
    for (int u = 0; u < 4; u++) {
        const int d = tid + u * 256;
        const float val = er[d] + tanhf(ar[d]);
        v[u] = val; s += val; ss += val * val;
    }
    s = wred_sum(s); ss = wred_sum(ss);
    if ((tid & 63) == 0) { sm[tid >> 6] = s; sm[4 + (tid >> 6)] = ss; }
    __syncthreads();
    s  = (sm[0] + sm[1]) + (sm[2] + sm[3]);
    ss = (sm[4] + sm[5]) + (sm[6] + sm[7]);
    const float mean = s * (1.f / 1024.f);
    const float var = ss * (1.f / 1024.f) - mean * mean;
    const float rstd = rsqrtf(var + 1e-5f);
    #pragma unroll
    for (int u = 0; u < 4; u++) {
        const int d = tid + u * 256;
        const float y = (v[u] - mean) * rstd * g[d] + be[d];
        orow[d] = valid ? y : 0.f;
    }
}

__global__ __launch_bounds__(256)
void ln2_kernel(const float* __restrict__ hp, const float* __restrict__ g,
                const float* __restrict__ be, float* __restrict__ out) {
    __shared__ float sm[8];
    const int r = blockIdx.x;
    const float* src = hp + (size_t)r * 512;
    float* orow = out + (size_t)r * 512;
    const int tid = threadIdx.x;
    float v[2]; float s = 0.f, ss = 0.f;
    #pragma unroll
    for (int u = 0; u < 2; u++) {
        const int d = tid + u * 256;
        const float xx = src[d];
        const float val = 0.5f * xx * (1.f + erff(xx * 0.7071067811865475f)); // exact gelu
        v[u] = val; s += val; ss += val * val;
    }
    s = wred_sum(s); ss = wred_sum(ss);
    if ((tid & 63) == 0) { sm[tid >> 6] = s; sm[4 + (tid >> 6)] = ss; }
    __syncthreads();
    s  = (sm[0] + sm[1]) + (sm[2] + sm[3]);
    ss = (sm[4] + sm[5]) + (sm[6] + sm[7]);
    const float mean = s * (1.f / 512.f);
    const float var = ss * (1.f / 512.f) - mean * mean;
    const float rstd = rsqrtf(var + 1e-5f);
    #pragma unroll
    for (int u = 0; u < 2; u++) {
        const int d = tid + u * 256;
        orow[d] = (v[u] - mean) * rstd * g[d] + be[d];
    }
}

// ---------------- host launcher ------------------------------------------
extern "C" void kernel_launch(void* const* d_in, const int* in_sizes, int n_in,
                              void* d_out, int out_size, void* d_ws, size_t ws_size,
                              hipStream_t stream) {
    const int*   x    = (const int*)  d_in[0];
    const float* emb  = (const float*)d_in[1];
    const float* Wf0  = (const float*)d_in[2];
    const float* bf0  = (const float*)d_in[3];
    const float* Wb0  = (const float*)d_in[4];
    const float* bb0  = (const float*)d_in[5];
    const float* Wf1  = (const float*)d_in[6];
    const float* bf1  = (const float*)d_in[7];
    const float* Wb1  = (const float*)d_in[8];
    const float* bb1  = (const float*)d_in[9];
    const float* h0f  = (const float*)d_in[10];
    const float* c0f  = (const float*)d_in[11];
    const float* h0b  = (const float*)d_in[12];
    const float* c0b  = (const float*)d_in[13];
    const float* Wq   = (const float*)d_in[14];
    const float* bq   = (const float*)d_in[15];
    const float* Wao  = (const float*)d_in[16];
    const float* bao  = (const float*)d_in[17];
    const float* ln1g = (const float*)d_in[18];
    const float* ln1b = (const float*)d_in[19];
    const float* Wh   = (const float*)d_in[20];
    const float* bh   = (const float*)d_in[21];
    const float* ln2g = (const float*)d_in[22];
    const float* ln2b = (const float*)d_in[23];
    const float* Wp   = (const float*)d_in[24];
    const float* obia = (const float*)d_in[25];
    float* out = (float*)d_out;
    float* ws  = (float*)d_ws;

    // Arena inside d_out (524 MB; intermediates ~200 MB, fully overwritten by
    // the final GEMM which only reads head (in d_ws) + Wp + out_bias).
    float* emb_seq = out;                                  // 2M floats
    float* xgf  = out + (size_t)2 * 1024 * 1024;           // 8M (reused layer0/1)
    float* xgb  = xgf + (size_t)8 * 1024 * 1024;           // 8M
    float* lin1 = xgb + (size_t)8 * 1024 * 1024;           // 4M
    float* enc  = lin1 + (size_t)4 * 1024 * 1024;          // 4M
    float* qry  = enc  + (size_t)4 * 1024 * 1024;          // 4M
    float* att  = qry  + (size_t)4 * 1024 * 1024;          // 2M
    float* cat  = att  + (size_t)2 * 1024 * 1024;          // 8M
    float* aop  = cat  + (size_t)8 * 1024 * 1024;          // 4M
    float* refd = aop  + (size_t)4 * 1024 * 1024;          // 4M
    float* hpre = refd + (size_t)4 * 1024 * 1024;          // 2M -> 50M total

    float* head = ws;                                      // 2M floats
    float* hbuf = ws + (size_t)2 * 1024 * 1024;            // 16384 floats
    unsigned int* slots = (unsigned int*)(hbuf + 2 * 2 * NB * HD); // 256 uints

    init_slots<<<1, 256, 0, stream>>>(slots);
    embed_kernel<<<NROWS, 128, 0, stream>>>(x, emb, emb_seq);
    // layer 0 x-gates (bias fused)
    gemm_f16<0><<<dim3(GD/128, NROWS/128, 1), 256, 0, stream>>>(emb_seq, ED, 0, Wf0, GD, 0, bf0, xgf, GD, 0, ED);
    gemm_f16<0><<<dim3(GD/128, NROWS/128, 1), 256, 0, stream>>>(emb_seq, ED, 0, Wb0, GD, 0, bb0, xgb, GD, 0, ED);
    lstm_layer<<<128, 128, 0, stream>>>(xgf, xgb, Wf0, Wb0, ED, h0f, c0f, h0b, c0b, x, lin1, hbuf, slots);
    // layer 1 x-gates (K = 2H = 1024)
    gemm_f16<0><<<dim3(GD/128, NROWS/128, 1), 256, 0, stream>>>(lin1, 1024, 0, Wf1, GD, 0, bf1, xgf, GD, 0, 1024);
    gemm_f16<0><<<dim3(GD/128, NROWS/128, 1), 256, 0, stream>>>(lin1, 1024, 0, Wb1, GD, 0, bb1, xgb, GD, 0, 1024);
    lstm_layer<<<128, 128, 0, stream>>>(xgf, xgb, Wf1, Wb1, 1024, h0f + 512, c0f + 512, h0b + 512, c0b + 512, x, enc, hbuf, slots + 128);
    // attention
    gemm_f16<0><<<dim3(1024/128, NROWS/128, 1), 256, 0, stream>>>(enc, 1024, 0, Wq, 1024, 0, bq, qry, 1024, 0, 1024);
    gemm_f16<1><<<dim3(4, 4, 8), 256, 0, stream>>>(qry, 1024, (long long)512*1024, enc, 1024, (long long)512*1024, nullptr, att, 512, (long long)512*512, 1024);
    softmax_kernel<<<NROWS, 256, 0, stream>>>(att, x);
    copycat_kernel<<<NROWS, 256, 0, stream>>>(enc, cat);
    gemm_f16<0><<<dim3(8, 4, 8), 256, 0, stream>>>(att, 512, (long long)512*512, enc, 1024, (long long)512*1024, nullptr, cat + 1024, 2048, (long long)512*2048, 512);
    // refine + LN1
    gemm_f16<0><<<dim3(1024/128, NROWS/128, 1), 256, 0, stream>>>(cat, 2048, 0, Wao, 1024, 0, bao, aop, 1024, 0, 2048);
    ln1_kernel<<<NROWS, 256, 0, stream>>>(enc, aop, ln1g, ln1b, x, refd);
    // head + LN2
    gemm_f16<0><<<dim3(512/128, NROWS/128, 1), 256, 0, stream>>>(refd, 1024, 0, Wh, 512, 0, bh, hpre, 512, 0, 1024);
    ln2_kernel<<<NROWS, 256, 0, stream>>>(hpre, ln2g, ln2b, head);
    // vocab projection (writes every element of d_out)
    gemm_f16<0><<<dim3(32000/128, NROWS/128, 1), 256, 0, stream>>>(head, 512, 0, Wp, 32000, 0, obia, out, 32000, 0, 512);
}